// Round 2
// baseline (108.784 us; speedup 1.0000x reference)
//
#include <hip/hip_runtime.h>

#define BB 4
#define CIN 3
#define HH 512
#define WW 512
#define KK 9
#define COUT 3
#define HO 510
#define WO 510
#define HW (HH * WW)
#define HOWO (HO * WO)

__global__ __launch_bounds__(256) void deform_fused_kernel(
    const float* __restrict__ x,   // [B, CIN, H, W]
    const float* __restrict__ w1,  // [18, CIN, 3, 3] -> flat [18][27]
    const float* __restrict__ b1,  // [18]
    const float* __restrict__ w2,  // [COUT, CIN, 3, 3] -> flat [(o*3+c)*9+k]
    const float* __restrict__ b2,  // [COUT]
    float* __restrict__ out)       // [B, COUT, HO, WO]
{
    constexpr int WP = WO / 2;  // 255 pixel-pairs per output row
    const int idx = blockIdx.x * blockDim.x + threadIdx.x;
    const int total = BB * HO * WP;
    if (idx >= total) return;

    const int jp = idx % WP;
    const int t1 = idx / WP;
    const int i = t1 % HO;
    const int b = t1 / HO;
    const int j = jp * 2;

    const float* xb = x + b * (CIN * HW);

    // Patch covering both pixels: rows i..i+2, cols j..j+3, all 3 channels.
    // One float4 per (c, r) feeds both pixels' 3x3 windows.
    float patch[CIN][3][4];
#pragma unroll
    for (int c = 0; c < CIN; ++c)
#pragma unroll
        for (int r = 0; r < 3; ++r) {
            const float4 v =
                *reinterpret_cast<const float4*>(&xb[c * HW + (i + r) * WW + j]);
            patch[c][r][0] = v.x;
            patch[c][r][1] = v.y;
            patch[c][r][2] = v.z;
            patch[c][r][3] = v.w;
        }

    float acc00 = b2[0], acc01 = b2[1], acc02 = b2[2];
    float acc10 = b2[0], acc11 = b2[1], acc12 = b2[2];

#pragma unroll
    for (int k = 0; k < KK; ++k) {
        const int ky = k / 3;
        const int kx = k % 3;

        // conv1 for both pixels; weights are uniform -> SGPR (s_load), so
        // each line is a v_fmac with one scalar operand.
        float dy0 = b1[2 * k], dx0 = b1[2 * k + 1];
        float dy1 = dy0, dx1 = dx0;
        int t = 0;
#pragma unroll
        for (int c = 0; c < CIN; ++c)
#pragma unroll
            for (int r = 0; r < 3; ++r)
#pragma unroll
                for (int s = 0; s < 3; ++s, ++t) {
                    const float wy = w1[(2 * k) * 27 + t];
                    const float wx = w1[(2 * k + 1) * 27 + t];
                    const float p0 = patch[c][r][s];
                    const float p1 = patch[c][r][s + 1];
                    dy0 += p0 * wy;
                    dx0 += p0 * wx;
                    dy1 += p1 * wy;
                    dx1 += p1 * wx;
                }

#pragma unroll
        for (int p = 0; p < 2; ++p) {
            const float dy = p ? dy1 : dy0;
            const float dx = p ? dx1 : dx0;
            const float sy = (float)(i + ky) + dy;
            const float sx = (float)(j + p + kx) + dx;
            const float y0f = floorf(sy);
            const float x0f = floorf(sx);
            const float fy = sy - y0f;
            const float fx = sx - x0f;
            const int y0 = (int)y0f;
            const int x0 = (int)x0f;

            float v0 = 0.f, v1 = 0.f, v2 = 0.f;
#pragma unroll
            for (int cy = 0; cy < 2; ++cy) {
                const int iy = y0 + cy;
                const float wyf = cy ? fy : (1.f - fy);
                const bool vy = (iy >= 0) && (iy < HH);
                const int iyc = iy < 0 ? 0 : (iy > HH - 1 ? HH - 1 : iy);
#pragma unroll
                for (int cx = 0; cx < 2; ++cx) {
                    const int ix = x0 + cx;
                    const float wxf = cx ? fx : (1.f - fx);
                    const bool vx = (ix >= 0) && (ix < WW);
                    const int ixc = ix < 0 ? 0 : (ix > WW - 1 ? WW - 1 : ix);
                    const float wgt = (vy && vx) ? (wyf * wxf) : 0.f;
                    const int off = iyc * WW + ixc;
                    v0 += wgt * xb[0 * HW + off];
                    v1 += wgt * xb[1 * HW + off];
                    v2 += wgt * xb[2 * HW + off];
                }
            }

            // conv2 accumulate (w2 uniform -> SGPR)
            const float c00 = w2[(0 * CIN + 0) * KK + k];
            const float c01 = w2[(0 * CIN + 1) * KK + k];
            const float c02 = w2[(0 * CIN + 2) * KK + k];
            const float c10 = w2[(1 * CIN + 0) * KK + k];
            const float c11 = w2[(1 * CIN + 1) * KK + k];
            const float c12 = w2[(1 * CIN + 2) * KK + k];
            const float c20 = w2[(2 * CIN + 0) * KK + k];
            const float c21 = w2[(2 * CIN + 1) * KK + k];
            const float c22 = w2[(2 * CIN + 2) * KK + k];
            const float r0 = c00 * v0 + c01 * v1 + c02 * v2;
            const float r1 = c10 * v0 + c11 * v1 + c12 * v2;
            const float r2 = c20 * v0 + c21 * v1 + c22 * v2;
            if (p == 0) {
                acc00 += r0; acc01 += r1; acc02 += r2;
            } else {
                acc10 += r0; acc11 += r1; acc12 += r2;
            }
        }
    }

    float* ob = out + b * (COUT * HOWO) + i * WO + j;
    {
        float2 st;
        st.x = acc00; st.y = acc10;
        *reinterpret_cast<float2*>(&ob[0 * HOWO]) = st;
        st.x = acc01; st.y = acc11;
        *reinterpret_cast<float2*>(&ob[1 * HOWO]) = st;
        st.x = acc02; st.y = acc12;
        *reinterpret_cast<float2*>(&ob[2 * HOWO]) = st;
    }
}

extern "C" void kernel_launch(void* const* d_in, const int* in_sizes, int n_in,
                              void* d_out, int out_size, void* d_ws, size_t ws_size,
                              hipStream_t stream) {
    const float* x  = (const float*)d_in[0];
    const float* w1 = (const float*)d_in[1];
    const float* b1 = (const float*)d_in[2];
    const float* w2 = (const float*)d_in[3];
    const float* b2 = (const float*)d_in[4];
    float* out = (float*)d_out;

    const int total = BB * HO * (WO / 2);
    const int block = 256;
    const int grid = (total + block - 1) / block;
    deform_fused_kernel<<<grid, block, 0, stream>>>(x, w1, b1, w2, b2, out);
}

// Round 3
// 64.499 us; speedup vs baseline: 1.6866x; 1.6866x over previous
//
#include <hip/hip_runtime.h>

#define BB 4
#define CIN 3
#define HH 512
#define WW 512
#define KK 9
#define COUT 3
#define HO 510
#define WO 510
#define HW (HH * WW)
#define HOWO (HO * WO)

#define XT_BYTES ((size_t)BB * HH * WW * 4 * sizeof(float))
#define OFFS_BYTES ((size_t)BB * KK * HOWO * sizeof(unsigned int))
#define WS_NEED (XT_BYTES + OFFS_BYTES)

__device__ __forceinline__ float comp3(const float4& v, int c) {
    return c == 0 ? v.x : (c == 1 ? v.y : v.z);
}

__device__ __forceinline__ unsigned int pack2bf16(float a, float b) {
    unsigned int ba = __float_as_uint(a);
    unsigned int bb = __float_as_uint(b);
    ba = ba + 0x7fffu + ((ba >> 16) & 1u);  // rtne fp32->bf16
    bb = bb + 0x7fffu + ((bb >> 16) & 1u);
    return (ba >> 16) | (bb & 0xffff0000u);
}

// ---------------- kernel 1: NCHW -> NHW4 repack ----------------
__global__ __launch_bounds__(256) void repack_nhwc(
    const float* __restrict__ x, float4* __restrict__ xT)
{
    const int idx = blockIdx.x * blockDim.x + threadIdx.x;
    const int total = BB * HH * WW;
    if (idx >= total) return;
    const int b = idx / HW;
    const int p = idx - b * HW;
    const float* xb = x + (size_t)b * CIN * HW;
    float4 v;
    v.x = xb[0 * HW + p];
    v.y = xb[1 * HW + p];
    v.z = xb[2 * HW + p];
    v.w = 0.f;
    xT[idx] = v;
}

// ---------------- kernel 2: conv1 -> packed bf16 offsets ----------------
// offs layout: [B][K][HO][WO], each dword = (bf16 dy | bf16 dx << 16)
__global__ __launch_bounds__(256, 4) void conv1_offsets(
    const float4* __restrict__ xT,  // [B][H][W] float4
    const float* __restrict__ w1,   // [18][3][3][3]
    const float* __restrict__ b1,   // [18]
    unsigned int* __restrict__ offs)
{
    // reordered weights: s_w[k*54 + t2*2 + w], t2 = r*9 + s*3 + c, ch = 2k+w
    __shared__ float s_w[KK * 27 * 2];
    __shared__ float s_b[18];
    for (int t = threadIdx.x; t < KK * 27 * 2; t += 256) {
        const int k = t / 54;
        const int rem = t % 54;
        const int t2 = rem >> 1;
        const int w = rem & 1;
        const int r = t2 / 9;
        const int s = (t2 % 9) / 3;
        const int c = t2 % 3;
        s_w[t] = w1[(2 * k + w) * 27 + c * 9 + r * 3 + s];
    }
    if (threadIdx.x < 18) s_b[threadIdx.x] = b1[threadIdx.x];
    __syncthreads();

    constexpr int WP = WO / 2;
    const int idx = blockIdx.x * 256 + threadIdx.x;
    if (idx >= BB * HO * WP) return;
    const int jp = idx % WP;
    const int t1 = idx / WP;
    const int i = t1 % HO;
    const int b = t1 / HO;
    const int j = jp * 2;

    const float4* xb4 = xT + (size_t)b * HW;
    float4 patch[3][4];
#pragma unroll
    for (int r = 0; r < 3; ++r)
#pragma unroll
        for (int cc = 0; cc < 4; ++cc)
            patch[r][cc] = xb4[(i + r) * WW + j + cc];

#pragma unroll
    for (int k = 0; k < KK; ++k) {
        float dy0 = s_b[2 * k], dx0 = s_b[2 * k + 1];
        float dy1 = dy0, dx1 = dx0;
        const float* wk = &s_w[k * 54];
#pragma unroll
        for (int r = 0; r < 3; ++r)
#pragma unroll
            for (int s = 0; s < 3; ++s)
#pragma unroll
                for (int c = 0; c < 3; ++c) {
                    const int t2 = r * 9 + s * 3 + c;
                    const float wy = wk[t2 * 2];
                    const float wx = wk[t2 * 2 + 1];
                    const float p0 = comp3(patch[r][s], c);
                    const float p1 = comp3(patch[r][s + 1], c);
                    dy0 += p0 * wy;
                    dx0 += p0 * wx;
                    dy1 += p1 * wy;
                    dx1 += p1 * wx;
                }
        uint2 st;
        st.x = pack2bf16(dy0, dx0);
        st.y = pack2bf16(dy1, dx1);
        *reinterpret_cast<uint2*>(
            &offs[((size_t)(b * KK + k)) * HOWO + i * WO + j]) = st;
    }
}

// ---------------- kernel 3: bilinear gather + conv2 ----------------
__global__ __launch_bounds__(256, 4) void deform_gather(
    const float4* __restrict__ xT,
    const unsigned int* __restrict__ offs,
    const float* __restrict__ w2,  // [3][3][3][3]
    const float* __restrict__ b2,  // [3]
    float* __restrict__ out)
{
    // s_w2 padded: [k][12], first 9 = o*3+c
    __shared__ float s_w2[KK * 12];
    __shared__ float s_b2[COUT];
    for (int t = threadIdx.x; t < KK * 12; t += 256) {
        const int k = t / 12;
        const int q = t % 12;
        s_w2[t] = (q < 9) ? w2[(q / 3) * 27 + (q % 3) * 9 + k] : 0.f;
    }
    if (threadIdx.x < COUT) s_b2[threadIdx.x] = b2[threadIdx.x];
    __syncthreads();

    const int idx = blockIdx.x * 256 + threadIdx.x;
    if (idx >= BB * HOWO) return;
    const int j = idx % WO;
    const int t1 = idx / WO;
    const int i = t1 % HO;
    const int b = t1 / HO;

    const size_t obase = (size_t)b * KK * HOWO + i * WO + j;
    unsigned int u[KK];
#pragma unroll
    for (int k = 0; k < KK; ++k) u[k] = offs[obase + (size_t)k * HOWO];

    const float4* xb4 = xT + (size_t)b * HW;
    const float fi = (float)i;
    const float fj = (float)j;

    float acc0 = s_b2[0], acc1 = s_b2[1], acc2 = s_b2[2];

#pragma unroll
    for (int k = 0; k < KK; ++k) {
        const float dy = __uint_as_float(u[k] << 16);
        const float dx = __uint_as_float(u[k] & 0xffff0000u);
        const float sy = fi + (float)(k / 3) + dy;
        const float sx = fj + (float)(k % 3) + dx;
        const float y0f = floorf(sy);
        const float x0f = floorf(sx);
        const float fy = sy - y0f;
        const float fx = sx - x0f;
        const int y0 = (int)y0f;
        const int x0 = (int)x0f;
        const int y1 = y0 + 1;
        const int x1 = x0 + 1;

        // validity folded into 1-D lerp weights -> corner weights are pure products
        const float wy0 = ((unsigned)y0 < (unsigned)HH) ? (1.f - fy) : 0.f;
        const float wy1 = ((unsigned)y1 < (unsigned)HH) ? fy : 0.f;
        const float wx0 = ((unsigned)x0 < (unsigned)WW) ? (1.f - fx) : 0.f;
        const float wx1 = ((unsigned)x1 < (unsigned)WW) ? fx : 0.f;

        const int y0c = min(max(y0, 0), HH - 1);
        const int y1c = min(max(y1, 0), HH - 1);
        const int x0c = min(max(x0, 0), WW - 1);
        const int x1c = min(max(x1, 0), WW - 1);

        const float4 c00 = xb4[y0c * WW + x0c];
        const float4 c01 = xb4[y0c * WW + x1c];
        const float4 c10 = xb4[y1c * WW + x0c];
        const float4 c11 = xb4[y1c * WW + x1c];

        const float w00 = wy0 * wx0, w01 = wy0 * wx1;
        const float w10 = wy1 * wx0, w11 = wy1 * wx1;

        const float v0 = w00 * c00.x + w01 * c01.x + w10 * c10.x + w11 * c11.x;
        const float v1 = w00 * c00.y + w01 * c01.y + w10 * c10.y + w11 * c11.y;
        const float v2 = w00 * c00.z + w01 * c01.z + w10 * c10.z + w11 * c11.z;

        const float4* wk4 = reinterpret_cast<const float4*>(&s_w2[k * 12]);
        const float4 a = wk4[0];
        const float4 bb = wk4[1];
        const float cw = s_w2[k * 12 + 8];
        acc0 += a.x * v0 + a.y * v1 + a.z * v2;
        acc1 += a.w * v0 + bb.x * v1 + bb.y * v2;
        acc2 += bb.z * v0 + bb.w * v1 + cw * v2;
    }

    float* ob = out + (size_t)b * COUT * HOWO + (size_t)i * WO + j;
    ob[0 * HOWO] = acc0;
    ob[1 * HOWO] = acc1;
    ob[2 * HOWO] = acc2;
}

// ---------------- fallback: R0 fused kernel (used if ws too small) ----------
__global__ __launch_bounds__(256) void deform_fused_kernel(
    const float* __restrict__ x, const float* __restrict__ w1,
    const float* __restrict__ b1, const float* __restrict__ w2,
    const float* __restrict__ b2, float* __restrict__ out)
{
    __shared__ float s_w1[18 * 27];
    __shared__ float s_b1[18];
    __shared__ float s_w2[COUT * CIN * KK];
    __shared__ float s_b2[COUT];
    for (int t = threadIdx.x; t < 18 * 27; t += blockDim.x) s_w1[t] = w1[t];
    if (threadIdx.x < 18) s_b1[threadIdx.x] = b1[threadIdx.x];
    if (threadIdx.x < COUT * CIN * KK) s_w2[threadIdx.x] = w2[threadIdx.x];
    if (threadIdx.x < COUT) s_b2[threadIdx.x] = b2[threadIdx.x];
    __syncthreads();
    const int idx = blockIdx.x * blockDim.x + threadIdx.x;
    if (idx >= BB * HOWO) return;
    const int j = idx % WO;
    const int tmp = idx / WO;
    const int i = tmp % HO;
    const int b = tmp / HO;
    const float* xb = x + (size_t)b * CIN * HW;
    float patch[CIN][3][3];
#pragma unroll
    for (int c = 0; c < CIN; ++c)
#pragma unroll
        for (int r = 0; r < 3; ++r)
#pragma unroll
            for (int s = 0; s < 3; ++s)
                patch[c][r][s] = xb[c * HW + (i + r) * WW + (j + s)];
    float acc0 = s_b2[0], acc1 = s_b2[1], acc2 = s_b2[2];
#pragma unroll
    for (int k = 0; k < KK; ++k) {
        const int ky = k / 3, kx = k % 3;
        float dy = s_b1[2 * k], dx = s_b1[2 * k + 1];
        const float* wy = &s_w1[(2 * k) * 27];
        const float* wx = &s_w1[(2 * k + 1) * 27];
        int t = 0;
#pragma unroll
        for (int c = 0; c < CIN; ++c)
#pragma unroll
            for (int r = 0; r < 3; ++r)
#pragma unroll
                for (int s = 0; s < 3; ++s, ++t) {
                    const float pv = patch[c][r][s];
                    dy += pv * wy[t];
                    dx += pv * wx[t];
                }
        const float sy = (float)(i + ky) + dy;
        const float sx = (float)(j + kx) + dx;
        const float y0f = floorf(sy), x0f = floorf(sx);
        const float fy = sy - y0f, fx = sx - x0f;
        const int y0 = (int)y0f, x0 = (int)x0f;
        float v0 = 0.f, v1 = 0.f, v2 = 0.f;
#pragma unroll
        for (int cy = 0; cy < 2; ++cy) {
            const int iy = y0 + cy;
            const float wyf = cy ? fy : (1.f - fy);
            const bool vy = (iy >= 0) && (iy < HH);
            const int iyc = iy < 0 ? 0 : (iy > HH - 1 ? HH - 1 : iy);
#pragma unroll
            for (int cx = 0; cx < 2; ++cx) {
                const int ix = x0 + cx;
                const float wxf = cx ? fx : (1.f - fx);
                const bool vx = (ix >= 0) && (ix < WW);
                const int ixc = ix < 0 ? 0 : (ix > WW - 1 ? WW - 1 : ix);
                const float wgt = (vy && vx) ? (wyf * wxf) : 0.f;
                const int off = iyc * WW + ixc;
                v0 += wgt * xb[0 * HW + off];
                v1 += wgt * xb[1 * HW + off];
                v2 += wgt * xb[2 * HW + off];
            }
        }
#pragma unroll
        for (int o = 0; o < COUT; ++o) {
            const float c0 = s_w2[(o * CIN + 0) * KK + k];
            const float c1 = s_w2[(o * CIN + 1) * KK + k];
            const float c2 = s_w2[(o * CIN + 2) * KK + k];
            const float contrib = c0 * v0 + c1 * v1 + c2 * v2;
            if (o == 0) acc0 += contrib;
            else if (o == 1) acc1 += contrib;
            else acc2 += contrib;
        }
    }
    float* ob = out + (size_t)b * COUT * HOWO + (size_t)i * WO + j;
    ob[0 * HOWO] = acc0;
    ob[1 * HOWO] = acc1;
    ob[2 * HOWO] = acc2;
}

extern "C" void kernel_launch(void* const* d_in, const int* in_sizes, int n_in,
                              void* d_out, int out_size, void* d_ws, size_t ws_size,
                              hipStream_t stream) {
    const float* x  = (const float*)d_in[0];
    const float* w1 = (const float*)d_in[1];
    const float* b1 = (const float*)d_in[2];
    const float* w2 = (const float*)d_in[3];
    const float* b2 = (const float*)d_in[4];
    float* out = (float*)d_out;

    if (ws_size >= WS_NEED) {
        float4* xT = (float4*)d_ws;
        unsigned int* offs = (unsigned int*)((char*)d_ws + XT_BYTES);

        {
            const int total = BB * HH * WW;
            repack_nhwc<<<(total + 255) / 256, 256, 0, stream>>>(x, xT);
        }
        {
            const int total = BB * HO * (WO / 2);
            conv1_offsets<<<(total + 255) / 256, 256, 0, stream>>>(xT, w1, b1, offs);
        }
        {
            const int total = BB * HOWO;
            deform_gather<<<(total + 255) / 256, 256, 0, stream>>>(xT, offs, w2, b2, out);
        }
    } else {
        const int total = BB * HOWO;
        deform_fused_kernel<<<(total + 255) / 256, 256, 0, stream>>>(x, w1, b1, w2, b2, out);
    }
}